// Round 8
// baseline (297.737 us; speedup 1.0000x reference)
//
#include <hip/hip_runtime.h>
#include <stdint.h>

typedef unsigned short u16;
typedef unsigned int   u32;

#define NB   2
#define NS   2048
#define NDIM 1024
#define NH   16
#define NDH  64
// SCALE * log2(e) = 0.125 * 1.4426950408889634
#define QSCALE 0.18033688011112042f

typedef __bf16 bf16x8 __attribute__((ext_vector_type(8)));
typedef float  f32x4  __attribute__((ext_vector_type(4)));

#define MFMA_BF16(a,b,c) __builtin_amdgcn_mfma_f32_16x16x32_bf16((a),(b),(c),0,0,0)

// ---------------- ws layout (bytes) ----------------
#define XBF_OFF   (256)                          // 8 MB x bf16; reused as combined attention output
#define WD_OFF    (XBF_OFF  + 8*1024*1024)       // 8 MB dense quaternion weights (q,k,v,o)
#define BIAS_OFF  (WD_OFF   + 8*1024*1024)       // 16 KB fp32 biases
#define QB_OFF    (BIAS_OFF + 16384)             // 8 MB Q (bh,s,d) bf16 (roped, pre-scaled)
#define KB_OFF    (QB_OFF   + 8*1024*1024)       // 8 MB K (bh,s,d) (roped)
#define VT_OFF    (KB_OFF   + 8*1024*1024)       // 8 MB V^T (bh,d,s)
#define OP_OFF    (VT_OFF   + 8*1024*1024)       // 16 MB O partials bf16 [split][bh][s][d]
#define LP_OFF    (OP_OFF   + 16*1024*1024)      // 512 KB l partials fp32 [split][bh][s]

__device__ __forceinline__ float bf2f(u16 h){
  union { u32 u; float f; } v; v.u = ((u32)h) << 16; return v.f;
}
__device__ __forceinline__ u16 f2bf(float f){
  union { float f; u32 u; } v; v.f = f;
  u32 r = (v.u >> 16) & 1u;
  return (u16)((v.u + 0x7fffu + r) >> 16);
}
__device__ __forceinline__ float load_val(const void* p, int i, int isbf){
  return isbf ? bf2f(((const u16*)p)[i]) : ((const float*)p)[i];
}
__device__ __forceinline__ void gl_lds16(const u16* g, u16* l){
  __builtin_amdgcn_global_load_lds(
      (__attribute__((address_space(1))) void*)(uintptr_t)g,
      (__attribute__((address_space(3))) void*)(uintptr_t)l,
      16, 0, 0);
}

// ---------------- dtype detector ----------------
__global__ void detect_kernel(const u16* __restrict__ x, int* __restrict__ flag){
  __shared__ int cnt;
  if (threadIdx.x == 0) cnt = 0;
  __syncthreads();
  int ok = 0;
  int base = threadIdx.x * 16;
  for (int i = base; i < base + 16; ++i){
    u16 h = x[i];
    int e = (h >> 7) & 0xFF;
    if ((e > 96 && e < 158) || ((h & 0x7FFF) == 0)) ok++;
  }
  atomicAdd(&cnt, ok);
  __syncthreads();
  if (threadIdx.x == 0) *flag = (cnt > 3600) ? 1 : 0;
}

// ---------------- x -> bf16 ----------------
__global__ void conv_x_kernel(const void* __restrict__ xin, u16* __restrict__ xbf,
                              const int* __restrict__ flag){
  int isbf = *flag;
  int t = blockIdx.x * 256 + threadIdx.x;
  if (isbf){
    ((uint4*)xbf)[t] = ((const uint4*)xin)[t];
  } else {
    const float4* f4 = (const float4*)xin;
    float4 a = f4[2*t], b = f4[2*t+1];
    ushort4 lo = { f2bf(a.x), f2bf(a.y), f2bf(a.z), f2bf(a.w) };
    ushort4 hi = { f2bf(b.x), f2bf(b.y), f2bf(b.z), f2bf(b.w) };
    ((ushort4*)xbf)[2*t]   = lo;
    ((ushort4*)xbf)[2*t+1] = hi;
  }
}

// ---------------- dense quaternion weight build ----------------
struct QPtrs { const void* w[16]; const void* b[4]; };

__global__ void build_w_kernel(QPtrs ptrs, u16* __restrict__ wd,
                               float* __restrict__ biasf, const int* __restrict__ flag){
  int isbf = *flag;
  int idx = blockIdx.x * 256 + threadIdx.x;
  int n = idx & 255, m = (idx >> 8) & 255, c = (idx >> 16) & 3, p = idx >> 18;
  int src = m * 256 + n;
  float vr = load_val(ptrs.w[p*4+0], src, isbf);
  float vi = load_val(ptrs.w[p*4+1], src, isbf);
  float vj = load_val(ptrs.w[p*4+2], src, isbf);
  float vk = load_val(ptrs.w[p*4+3], src, isbf);
  float o0, o1, o2, o3;
  switch (c){
    case 0:  o0 = vr; o1 = -vi; o2 = -vj; o3 = -vk; break;
    case 1:  o0 = vi; o1 =  vr; o2 = -vj; o3 =  vk; break;
    case 2:  o0 = vj; o1 =  vi; o2 =  vr; o3 = -vk; break;
    default: o0 = vk; o1 = -vi; o2 =  vj; o3 =  vr; break;
  }
  ushort4 sv = { f2bf(o0), f2bf(o1), f2bf(o2), f2bf(o3) };
  *(ushort4*)&wd[(size_t)p * 1048576 + (size_t)(4*m + c) * 1024 + 4*n] = sv;
  if (idx < 4096){
    int pp = idx >> 10, oo = idx & 1023;
    biasf[idx] = load_val(ptrs.b[pp], oo, isbf);
  }
}

// ---------------- GEMM: X*Wqkv^T, 128x128 tile, NO LDS / NO BARRIERS ----------------
// Both MFMA operand fragments are lane-addressable from global: each wave
// streams its own A/B 16B fragment rows via global_load_dwordx4 with
// register double-buffering. Waves fully independent; L2-fed.
__global__ __launch_bounds__(256)
void gemm_qkv_kernel(const u16* __restrict__ A, const u16* __restrict__ Bw,
                     const float* __restrict__ bias,
                     u16* __restrict__ qb, u16* __restrict__ kb, u16* __restrict__ vt){
  int tid = threadIdx.x, w = tid >> 6, lane = tid & 63, quad = lane >> 4, l16 = lane & 15;
  int n0 = blockIdx.x * 128, m0 = blockIdx.y * 128;
  int mw = (w & 1) * 64, nw = (w >> 1) * 64;

  f32x4 acc[4][4];
#pragma unroll
  for (int i = 0; i < 4; ++i)
#pragma unroll
    for (int j = 0; j < 4; ++j) acc[i][j] = (f32x4){0.f, 0.f, 0.f, 0.f};

  const u16* pa = A  + (size_t)(m0 + mw + l16) * 1024 + quad * 8;
  const u16* pb = Bw + (size_t)(n0 + nw + l16) * 1024 + quad * 8;

  bf16x8 afc[4], bfc[4], afn[4], bfn[4];
#pragma unroll
  for (int t = 0; t < 4; ++t){
    afc[t] = *(const bf16x8*)(pa + (size_t)t * 16384);
    bfc[t] = *(const bf16x8*)(pb + (size_t)t * 16384);
  }

#pragma unroll 2
  for (int it = 0; it < 32; ++it){
    if (it < 31){
      int k1 = (it + 1) * 32;
#pragma unroll
      for (int t = 0; t < 4; ++t){
        afn[t] = *(const bf16x8*)(pa + (size_t)t * 16384 + k1);
        bfn[t] = *(const bf16x8*)(pb + (size_t)t * 16384 + k1);
      }
    }
#pragma unroll
    for (int mt = 0; mt < 4; ++mt)
#pragma unroll
      for (int nt = 0; nt < 4; ++nt)
        acc[mt][nt] = MFMA_BF16(afc[mt], bfc[nt], acc[mt][nt]);
#pragma unroll
    for (int t = 0; t < 4; ++t){ afc[t] = afn[t]; bfc[t] = bfn[t]; }
  }

  int proj = n0 >> 10;    // uniform per block
  if (proj == 2){
    // V^T: [bh][d][s]
#pragma unroll
    for (int mt = 0; mt < 4; ++mt){
      int row = m0 + mw + mt*16 + quad*4;
      int b = row >> 11, seq0 = row & 2047;
#pragma unroll
      for (int nt = 0; nt < 4; ++nt){
        int col = n0 + nw + nt*16 + l16;
        int o = col & 1023, h = o >> 6, d = o & 63;
        float bv = bias[col];
        ushort4 pv = { f2bf(acc[mt][nt][0] + bv), f2bf(acc[mt][nt][1] + bv),
                       f2bf(acc[mt][nt][2] + bv), f2bf(acc[mt][nt][3] + bv) };
        *(ushort4*)&vt[((size_t)((b*16 + h) * 64 + d)) * 2048 + seq0] = pv;
      }
    }
  } else {
    // Q/K with fused RoPE: out = co*v + sgn*si*partner (partner = lane xor (ax+1))
    float sc = (proj == 0) ? QSCALE : 1.0f;
    u16* dst = proj ? kb : qb;
    int c = l16 & 3;
#pragma unroll
    for (int nt = 0; nt < 4; ++nt){
      int col = n0 + nw + nt*16 + l16;
      int o = col & 1023, h = o >> 6, d = o & 63;
      int g = d >> 2;
      int ax = g % 3;
      int mask = ax + 1;
      int tbl = (ax == 0) ? 0xA : (ax == 1 ? 0x6 : 0xC);
      float sgn = ((tbl >> c) & 1) ? 1.f : -1.f;
      float inv = __builtin_amdgcn_exp2f(-(float)g * 0.8304820237218405f); // 10000^(-g/16)
      float bv = bias[col];
#pragma unroll
      for (int mt = 0; mt < 4; ++mt){
        int row0 = m0 + mw + mt*16 + quad*4;
        int b = row0 >> 11, s0 = row0 & 2047;
        size_t obase = ((size_t)((b*16 + h) * 2048 + s0)) * 64 + d;
#pragma unroll
        for (int r = 0; r < 4; ++r){
          float v = acc[mt][nt][r] + bv;
          float vp = __shfl_xor(v, mask);
          float ang = (float)(s0 + r) * inv;
          float co = __cosf(ang) * sc;
          float si = __sinf(ang) * sc * sgn;
          dst[obase + (size_t)r * 64] = f2bf(co * v + si * vp);
        }
      }
    }
  }
}

// ---------------- GEMM: attn-out * Wo^T -> d_out (r6 version: 64x128, LDS dbuf) ----------------
__global__ __launch_bounds__(256)
void gemm_o_kernel(const u16* __restrict__ A, const u16* __restrict__ Bw,
                   const float* __restrict__ bias, void* __restrict__ dout,
                   const int* __restrict__ flag){
  __shared__ u16 sA[2][64 * 32];
  __shared__ u16 sB[2][128 * 32];
  int tid = threadIdx.x, w = tid >> 6, lane = tid & 63, quad = lane >> 4, l16 = lane & 15;
  int n0 = blockIdx.x * 128, m0 = blockIdx.y * 64;

  f32x4 acc[2][4];
#pragma unroll
  for (int i = 0; i < 2; ++i)
#pragma unroll
    for (int j = 0; j < 4; ++j) acc[i][j] = (f32x4){0.f, 0.f, 0.f, 0.f};

  int cp = lane & 3, rl = lane >> 2;
  int gc = (cp ^ ((rl >> 1) & 3)) * 8;
  int xorv = ((l16 >> 1) & 3) * 8;
  int mw = (w & 1) * 32, nw = (w >> 1) * 64;

  auto stage = [&](int k0, int b){
#pragma unroll
    for (int i = 0; i < 3; ++i){
      int ch = w * 3 + i;
      int lr = (ch < 4 ? ch : ch - 4) * 16 + rl;
      int eo = (ch < 4 ? ch : ch - 4) * 512 + lane * 8;
      if (ch < 4) gl_lds16(A  + (size_t)(m0 + lr) * 1024 + k0 + gc, &sA[b][eo]);
      else        gl_lds16(Bw + (size_t)(n0 + lr) * 1024 + k0 + gc, &sB[b][eo]);
    }
  };

  stage(0, 0);
  for (int it = 0; it < 32; ++it){
    __syncthreads();
    if (it < 31) stage((it + 1) * 32, (it + 1) & 1);
    const u16* cA = sA[it & 1];
    const u16* cB = sB[it & 1];
    bf16x8 af[2], bfr[4];
#pragma unroll
    for (int mt = 0; mt < 2; ++mt)
      af[mt] = *(const bf16x8*)&cA[(mw + mt*16 + l16) * 32 + (quad*8 ^ xorv)];
#pragma unroll
    for (int nt = 0; nt < 4; ++nt)
      bfr[nt] = *(const bf16x8*)&cB[(nw + nt*16 + l16) * 32 + (quad*8 ^ xorv)];
#pragma unroll
    for (int mt = 0; mt < 2; ++mt)
#pragma unroll
      for (int nt = 0; nt < 4; ++nt)
        acc[mt][nt] = MFMA_BF16(af[mt], bfr[nt], acc[mt][nt]);
  }

  int isbf = *flag;
#pragma unroll
  for (int mt = 0; mt < 2; ++mt){
    int row = m0 + mw + mt*16 + quad*4;
#pragma unroll
    for (int nt = 0; nt < 4; ++nt){
      int col = n0 + nw + nt*16 + l16;
      float bv = bias[col];
#pragma unroll
      for (int r = 0; r < 4; ++r){
        float val = acc[mt][nt][r] + bv;
        size_t addr = (size_t)(row + r) * 1024 + col;
        if (isbf) ((u16*)dout)[addr] = f2bf(val);
        else      ((float*)dout)[addr] = val;
      }
    }
  }
}

// ---------------- flash attention v4 (unchanged, verified) ----------------
#define SPT 20

__global__ __launch_bounds__(256, 3)
void attn_kernel(const u16* __restrict__ Q, const u16* __restrict__ K,
                 const u16* __restrict__ Vt, u16* __restrict__ OP,
                 float* __restrict__ LP){
  __shared__ u16 sK[2][4096];
  __shared__ u16 sPT[4][64 * SPT];
  int bh  = blockIdx.x;
  int spl = blockIdx.y;
  int qt  = 15 - (int)blockIdx.z;
  int tid = threadIdx.x, w = tid >> 6, lane = tid & 63, quad = lane >> 4, l16 = lane & 15;
  size_t kbase = (size_t)bh * 2048 * 64;
  size_t vbase = (size_t)bh * 64 * 2048;
  int rowbase = qt * 128 + w * 32;
  u16* spw = &sPT[w][0];

  bf16x8 qf[2][2];
#pragma unroll
  for (int g = 0; g < 2; ++g)
#pragma unroll
    for (int kc = 0; kc < 2; ++kc)
      qf[g][kc] = *(const bf16x8*)(Q + kbase + (size_t)(rowbase + g*16 + l16) * 64 + kc*32 + quad*8);

  f32x4 oaccT[2][4];
  float lsum[2][4];
#pragma unroll
  for (int g = 0; g < 2; ++g)
#pragma unroll
    for (int i = 0; i < 4; ++i){ oaccT[g][i] = (f32x4){0.f,0.f,0.f,0.f}; lsum[g][i] = 0.f; }

  int kt0 = spl ? (qt + 1) : 0;
  int ntiles = qt + 1;

  auto stage = [&](int kt, int b){
    int kcol = kt * 64;
#pragma unroll
    for (int p = 0; p < 2; ++p){
      int slot = w*128 + p*64 + lane;
      int row = slot >> 3, dc = (slot & 7) ^ (row & 7);
      gl_lds16(K + kbase + (size_t)(kcol + row) * 64 + dc*8, &sK[b][(w*128 + p*64) * 8]);
    }
  };

  stage(kt0, 0);
  for (int i = 0; i < ntiles; ++i){
    int kcol = (kt0 + i) * 64;
    __syncthreads();
    if (i + 1 < ntiles) stage(kt0 + i + 1, (i + 1) & 1);
    const u16* bK = sK[i & 1];

    if (kcol <= rowbase + 31){
      bf16x8 vf[4][2];
#pragma unroll
      for (int dn = 0; dn < 4; ++dn)
#pragma unroll
        for (int kc = 0; kc < 2; ++kc)
          vf[dn][kc] = *(const bf16x8*)(Vt + vbase + (size_t)(dn*16 + l16) * 2048
                                        + kcol + kc*32 + quad*8);
      bf16x8 bk[2][4];
#pragma unroll
      for (int kc = 0; kc < 2; ++kc)
#pragma unroll
        for (int nt = 0; nt < 4; ++nt){
          int rw = nt*16 + l16;
          int ch = ((kc*4 + quad) ^ (rw & 7)) * 8;
          bk[kc][nt] = *(const bf16x8*)&bK[rw*64 + ch];
        }
#pragma unroll
      for (int g = 0; g < 2; ++g){
        int G0 = rowbase + g*16;
        if (kcol <= G0 + 15){
          f32x4 sacc[4];
#pragma unroll
          for (int nt = 0; nt < 4; ++nt) sacc[nt] = (f32x4){0.f,0.f,0.f,0.f};
#pragma unroll
          for (int kc = 0; kc < 2; ++kc)
#pragma unroll
            for (int nt = 0; nt < 4; ++nt)
              sacc[nt] = MFMA_BF16(qf[g][kc], bk[kc][nt], sacc[nt]);

          if (kcol + 63 > G0){
#pragma unroll
            for (int nt = 0; nt < 4; ++nt){
              int col = kcol + nt*16 + l16;
              ushort4 pv;
#pragma unroll
              for (int r = 0; r < 4; ++r){
                int row = G0 + quad*4 + r;
                float pp = (col <= row) ? __builtin_amdgcn_exp2f(sacc[nt][r]) : 0.f;
                lsum[g][r] += pp;
                ((u16*)&pv)[r] = f2bf(pp);
              }
              *(ushort4*)&spw[(nt*16 + l16) * SPT + quad*4] = pv;
            }
          } else {
#pragma unroll
            for (int nt = 0; nt < 4; ++nt){
              ushort4 pv;
#pragma unroll
              for (int r = 0; r < 4; ++r){
                float pp = __builtin_amdgcn_exp2f(sacc[nt][r]);
                lsum[g][r] += pp;
                ((u16*)&pv)[r] = f2bf(pp);
              }
              *(ushort4*)&spw[(nt*16 + l16) * SPT + quad*4] = pv;
            }
          }
#pragma unroll
          for (int kc = 0; kc < 2; ++kc){
            bf16x8 pf;
#pragma unroll
            for (int j = 0; j < 8; ++j)
              pf[j] = ((const __bf16*)spw)[(kc*32 + quad*8 + j) * SPT + l16];
#pragma unroll
            for (int dn = 0; dn < 4; ++dn)
              oaccT[g][dn] = MFMA_BF16(vf[dn][kc], pf, oaccT[g][dn]);
          }
        }
      }
    }
  }

  float* scr = (float*)spw;
#pragma unroll
  for (int g = 0; g < 2; ++g)
#pragma unroll
    for (int r = 0; r < 4; ++r){
      float l = lsum[g][r];
      l += __shfl_xor(l, 1); l += __shfl_xor(l, 2);
      l += __shfl_xor(l, 4); l += __shfl_xor(l, 8);
      if (l16 == 0) scr[g*16 + quad*4 + r] = l;
    }
  float lrow[2];
#pragma unroll
  for (int g = 0; g < 2; ++g) lrow[g] = scr[g*16 + l16];

  size_t obase = ((size_t)(spl*32 + bh)) * 2048;
#pragma unroll
  for (int g = 0; g < 2; ++g){
    int row = rowbase + g*16 + l16;
    if (quad == 0) LP[obase + row] = lrow[g];
#pragma unroll
    for (int dn = 0; dn < 4; ++dn){
      ushort4 ov = { f2bf(oaccT[g][dn][0]), f2bf(oaccT[g][dn][1]),
                     f2bf(oaccT[g][dn][2]), f2bf(oaccT[g][dn][3]) };
      *(ushort4*)&OP[(obase + row) * 64 + dn*16 + quad*4] = ov;
    }
  }
}

// ---------------- combine splits -> Ab (b, s, h*64+d) bf16 ----------------
__global__ void combine_kernel(const u16* __restrict__ OP, const float* __restrict__ LP,
                               u16* __restrict__ Ab){
  int idx = blockIdx.x * 256 + threadIdx.x;
  int dc = idx & 7, s = (idx >> 3) & 2047, bh = idx >> 14;
  size_t r0 = (size_t)bh * 2048 + s, r1 = (size_t)(32 + bh) * 2048 + s;
  float invl = 1.f / (LP[r0] + LP[r1]);
  union { uint4 v; u16 h[8]; } a0, a1; ushort4 o[2];
  a0.v = *(const uint4*)&OP[r0 * 64 + dc*8];
  a1.v = *(const uint4*)&OP[r1 * 64 + dc*8];
#pragma unroll
  for (int p = 0; p < 2; ++p)
#pragma unroll
    for (int j = 0; j < 4; ++j)
      ((u16*)&o[p])[j] = f2bf((bf2f(a0.h[p*4+j]) + bf2f(a1.h[p*4+j])) * invl);
  int b = bh >> 4, h = bh & 15;
  u16* dst = &Ab[((size_t)(b*2048 + s)) * 1024 + h*64 + dc*8];
  *(ushort4*)dst = o[0];
  *(ushort4*)(dst + 4) = o[1];
}

// ---------------- launcher ----------------
extern "C" void kernel_launch(void* const* d_in, const int* in_sizes, int n_in,
                              void* d_out, int out_size, void* d_ws, size_t ws_size,
                              hipStream_t stream){
  (void)in_sizes; (void)n_in; (void)out_size; (void)ws_size;
  char* ws = (char*)d_ws;
  int*   flag  = (int*)ws;
  u16*   Xbf   = (u16*)(ws + XBF_OFF);
  u16*   Wd    = (u16*)(ws + WD_OFF);
  float* biasf = (float*)(ws + BIAS_OFF);
  u16*   Qb    = (u16*)(ws + QB_OFF);
  u16*   Kb    = (u16*)(ws + KB_OFF);
  u16*   Vt    = (u16*)(ws + VT_OFF);
  u16*   OP    = (u16*)(ws + OP_OFF);
  float* LP    = (float*)(ws + LP_OFF);
  u16*   Ab    = Xbf;

  detect_kernel<<<1, 256, 0, stream>>>((const u16*)d_in[0], flag);
  conv_x_kernel<<<2048, 256, 0, stream>>>(d_in[0], Xbf, flag);

  QPtrs ptrs;
  for (int p = 0; p < 4; ++p){
    for (int wi = 0; wi < 4; ++wi) ptrs.w[p*4 + wi] = d_in[2 + p*5 + wi];
    ptrs.b[p] = d_in[2 + p*5 + 4];
  }
  build_w_kernel<<<4096, 256, 0, stream>>>(ptrs, Wd, biasf, flag);

  gemm_qkv_kernel<<<dim3(24, 32), 256, 0, stream>>>(Xbf, Wd, biasf, Qb, Kb, Vt);
  attn_kernel<<<dim3(32, 2, 16), 256, 0, stream>>>(Qb, Kb, Vt, OP, LP);
  combine_kernel<<<2048, 256, 0, stream>>>(OP, LP, Ab);
  gemm_o_kernel<<<dim3(8, 64), 256, 0, stream>>>(Ab, Wd + 3*1048576, biasf + 3072,
                                                 d_out, flag);
}

// Round 9
// 259.323 us; speedup vs baseline: 1.1481x; 1.1481x over previous
//
#include <hip/hip_runtime.h>
#include <stdint.h>

typedef unsigned short u16;
typedef unsigned int   u32;

#define NB   2
#define NS   2048
#define NDIM 1024
#define NH   16
#define NDH  64
// SCALE * log2(e) = 0.125 * 1.4426950408889634
#define QSCALE 0.18033688011112042f

typedef __bf16 bf16x8 __attribute__((ext_vector_type(8)));
typedef float  f32x4  __attribute__((ext_vector_type(4)));

#define MFMA_BF16(a,b,c) __builtin_amdgcn_mfma_f32_16x16x32_bf16((a),(b),(c),0,0,0)

// ---------------- ws layout (bytes) ----------------
#define XBF_OFF   (256)                          // 8 MB x bf16
#define WD_OFF    (XBF_OFF  + 8*1024*1024)       // 8 MB dense quaternion weights (q,k,v,o)
#define BIAS_OFF  (WD_OFF   + 8*1024*1024)       // 16 KB fp32 biases
#define QB_OFF    (BIAS_OFF + 16384)             // 8 MB Q (bh,s,d) bf16 (roped, pre-scaled)
#define KB_OFF    (QB_OFF   + 8*1024*1024)       // 8 MB K (bh,s,d) (roped)
#define VT_OFF    (KB_OFF   + 8*1024*1024)       // 8 MB V^T (bh,d,s)
#define OP_OFF    (VT_OFF   + 8*1024*1024)       // 16 MB O partials bf16 [split][bh][s][d]
#define LP_OFF    (OP_OFF   + 16*1024*1024)      // 512 KB l partials fp32 [split][bh][s]

__device__ __forceinline__ float bf2f(u16 h){
  union { u32 u; float f; } v; v.u = ((u32)h) << 16; return v.f;
}
__device__ __forceinline__ u16 f2bf(float f){
  union { float f; u32 u; } v; v.f = f;
  u32 r = (v.u >> 16) & 1u;
  return (u16)((v.u + 0x7fffu + r) >> 16);
}
__device__ __forceinline__ float load_val(const void* p, int i, int isbf){
  return isbf ? bf2f(((const u16*)p)[i]) : ((const float*)p)[i];
}
__device__ __forceinline__ void gl_lds16(const u16* g, u16* l){
  __builtin_amdgcn_global_load_lds(
      (__attribute__((address_space(1))) void*)(uintptr_t)g,
      (__attribute__((address_space(3))) void*)(uintptr_t)l,
      16, 0, 0);
}
__device__ __forceinline__ int sane16(u16 h){
  int e = (h >> 7) & 0xFF;
  return ((e > 96 && e < 158) || ((h & 0x7FFF) == 0)) ? 1 : 0;
}

struct QPtrs { const void* w[16]; const void* b[4]; };

// ---------------- prep: x->bf16 conversion + dense weight build (self-detecting) ----------------
// blocks [0,2048): convert x.  blocks [2048,6144): build Wd + biases.
// Each block votes dtype from its own data; block 0 publishes flag for gemm_o.
__global__ void prep_kernel(const void* __restrict__ xin, u16* __restrict__ xbf,
                            QPtrs ptrs, u16* __restrict__ wd,
                            float* __restrict__ biasf, int* __restrict__ flag){
  __shared__ int cnt;
  int bx = blockIdx.x, tid = threadIdx.x;
  if (tid == 0) cnt = 0;
  __syncthreads();

  if (bx < 2048){
    // ---- conv_x part ----
    int t = bx * 256 + tid;
    uint4 v = ((const uint4*)xin)[t];        // 16B window; bf16 payload if bf16
    const u16* hv = (const u16*)&v;
    int ok = 0;
#pragma unroll
    for (int j = 0; j < 8; ++j) ok += sane16(hv[j]);
    atomicAdd(&cnt, ok);
    __syncthreads();
    int isbf = (cnt > 1700) ? 1 : 0;         // 2048 samples: bf16~2048, fp32~1270
    if (bx == 0 && tid == 0) *flag = isbf;
    if (isbf){
      ((uint4*)xbf)[t] = v;
    } else {
      const float4* f4 = (const float4*)xin;
      float4 a = f4[2*t], b = f4[2*t+1];
      ushort4 lo = { f2bf(a.x), f2bf(a.y), f2bf(a.z), f2bf(a.w) };
      ushort4 hi = { f2bf(b.x), f2bf(b.y), f2bf(b.z), f2bf(b.w) };
      ((ushort4*)xbf)[2*t]   = lo;
      ((ushort4*)xbf)[2*t+1] = hi;
    }
  } else {
    // ---- build_w part ----
    int idx = (bx - 2048) * 256 + tid;
    int n = idx & 255, m = (idx >> 8) & 255, c = (idx >> 16) & 3, p = idx >> 18;
    // vote on this proj's wr matrix (nonzero gaussian)
    const u16* probe = (const u16*)ptrs.w[p*4];
    int ok = sane16(probe[tid]) + sane16(probe[tid + 256]);
    atomicAdd(&cnt, ok);
    __syncthreads();
    int isbf = (cnt > 450) ? 1 : 0;          // 512 samples: bf16~512, fp32~317
    int src = m * 256 + n;
    float vr = load_val(ptrs.w[p*4+0], src, isbf);
    float vi = load_val(ptrs.w[p*4+1], src, isbf);
    float vj = load_val(ptrs.w[p*4+2], src, isbf);
    float vk = load_val(ptrs.w[p*4+3], src, isbf);
    float o0, o1, o2, o3;
    switch (c){
      case 0:  o0 = vr; o1 = -vi; o2 = -vj; o3 = -vk; break;
      case 1:  o0 = vi; o1 =  vr; o2 = -vj; o3 =  vk; break;
      case 2:  o0 = vj; o1 =  vi; o2 =  vr; o3 = -vk; break;
      default: o0 = vk; o1 = -vi; o2 =  vj; o3 =  vr; break;
    }
    ushort4 sv = { f2bf(o0), f2bf(o1), f2bf(o2), f2bf(o3) };
    *(ushort4*)&wd[(size_t)p * 1048576 + (size_t)(4*m + c) * 1024 + 4*n] = sv;
    if (idx < 4096){
      int pp = idx >> 10, oo = idx & 1023;
      biasf[idx] = load_val(ptrs.b[pp], oo, isbf);
    }
  }
}

// ---------------- GEMM: X*Wqkv^T, fused bias+RoPE epilogue (r6-proven) ----------------
__global__ __launch_bounds__(256)
void gemm_qkv_kernel(const u16* __restrict__ A, const u16* __restrict__ Bw,
                     const float* __restrict__ bias,
                     u16* __restrict__ qb, u16* __restrict__ kb, u16* __restrict__ vt){
  __shared__ u16 sA[2][128 * 32];
  __shared__ u16 sB[2][128 * 32];
  int tid = threadIdx.x, w = tid >> 6, lane = tid & 63, quad = lane >> 4, l16 = lane & 15;
  int n0 = blockIdx.x * 128, m0 = blockIdx.y * 128;

  f32x4 acc[4][4];
#pragma unroll
  for (int i = 0; i < 4; ++i)
#pragma unroll
    for (int j = 0; j < 4; ++j) acc[i][j] = (f32x4){0.f, 0.f, 0.f, 0.f};

  int cp = lane & 3, rl = lane >> 2;
  int gc = (cp ^ ((rl >> 1) & 3)) * 8;
  const u16* ga = A  + (size_t)(m0 + w*16 + rl) * 1024 + gc;
  const u16* gb = Bw + (size_t)(n0 + w*16 + rl) * 1024 + gc;
  int ldo = w * 512 + lane * 8;
  int xorv = ((l16 >> 1) & 3) * 8;
  int mw = (w & 1) * 64, nw = (w >> 1) * 64;

  auto stage = [&](int k0, int b){
#pragma unroll
    for (int i = 0; i < 2; ++i){
      gl_lds16(ga + (size_t)i * 65536 + k0, &sA[b][ldo + i * 2048]);
      gl_lds16(gb + (size_t)i * 65536 + k0, &sB[b][ldo + i * 2048]);
    }
  };

  stage(0, 0);
  for (int it = 0; it < 32; ++it){
    __syncthreads();
    if (it < 31) stage((it + 1) * 32, (it + 1) & 1);
    const u16* cA = sA[it & 1];
    const u16* cB = sB[it & 1];
    bf16x8 af[4], bfr[4];
#pragma unroll
    for (int mt = 0; mt < 4; ++mt)
      af[mt] = *(const bf16x8*)&cA[(mw + mt*16 + l16) * 32 + (quad*8 ^ xorv)];
#pragma unroll
    for (int nt = 0; nt < 4; ++nt)
      bfr[nt] = *(const bf16x8*)&cB[(nw + nt*16 + l16) * 32 + (quad*8 ^ xorv)];
#pragma unroll
    for (int mt = 0; mt < 4; ++mt)
#pragma unroll
      for (int nt = 0; nt < 4; ++nt)
        acc[mt][nt] = MFMA_BF16(af[mt], bfr[nt], acc[mt][nt]);
  }

  int proj = n0 >> 10;    // uniform per block
  if (proj == 2){
    // V^T: [bh][d][s]
#pragma unroll
    for (int mt = 0; mt < 4; ++mt){
      int row = m0 + mw + mt*16 + quad*4;
      int b = row >> 11, seq0 = row & 2047;
#pragma unroll
      for (int nt = 0; nt < 4; ++nt){
        int col = n0 + nw + nt*16 + l16;
        int o = col & 1023, h = o >> 6, d = o & 63;
        float bv = bias[col];
        ushort4 pv = { f2bf(acc[mt][nt][0] + bv), f2bf(acc[mt][nt][1] + bv),
                       f2bf(acc[mt][nt][2] + bv), f2bf(acc[mt][nt][3] + bv) };
        *(ushort4*)&vt[((size_t)((b*16 + h) * 64 + d)) * 2048 + seq0] = pv;
      }
    }
  } else {
    // Q/K with fused RoPE: out = co*v + sgn*si*partner (partner = lane xor (ax+1))
    float sc = (proj == 0) ? QSCALE : 1.0f;
    u16* dst = proj ? kb : qb;
    int c = l16 & 3;
#pragma unroll
    for (int nt = 0; nt < 4; ++nt){
      int col = n0 + nw + nt*16 + l16;
      int o = col & 1023, h = o >> 6, d = o & 63;
      int g = d >> 2;
      int ax = g % 3;
      int mask = ax + 1;
      int tbl = (ax == 0) ? 0xA : (ax == 1 ? 0x6 : 0xC);
      float sgn = ((tbl >> c) & 1) ? 1.f : -1.f;
      float inv = __builtin_amdgcn_exp2f(-(float)g * 0.8304820237218405f); // 10000^(-g/16)
      float bv = bias[col];
#pragma unroll
      for (int mt = 0; mt < 4; ++mt){
        int row0 = m0 + mw + mt*16 + quad*4;
        int b = row0 >> 11, s0 = row0 & 2047;
        size_t obase = ((size_t)((b*16 + h) * 2048 + s0)) * 64 + d;
#pragma unroll
        for (int r = 0; r < 4; ++r){
          float v = acc[mt][nt][r] + bv;
          float vp = __shfl_xor(v, mask);
          float ang = (float)(s0 + r) * inv;
          float co = __cosf(ang) * sc;
          float si = __sinf(ang) * sc * sgn;
          dst[obase + (size_t)r * 64] = f2bf(co * v + si * vp);
        }
      }
    }
  }
}

// ---------------- GEMM: (combine ∘ attn-out) * Wo^T -> d_out ----------------
// A-tile = normalized attention output computed on the fly from OP/LP partials:
// A[m][k] = (OP0[bh][s][d] + OP1[bh][s][d]) / (LP0+LP1),  bh=(m>>11)*16+(k>>6),
// s=m&2047, d=k&63.  A staged via VGPR->ds_write (stride 40, 16B-aligned);
// B staged via swizzled global_load_lds as r6.
__global__ __launch_bounds__(256)
void gemm_o_kernel(const u16* __restrict__ OP, const float* __restrict__ LP,
                   const u16* __restrict__ Bw, const float* __restrict__ bias,
                   void* __restrict__ dout, const int* __restrict__ flag){
  __shared__ u16 sA[2][64 * 40];
  __shared__ u16 sB[2][128 * 32];
  int tid = threadIdx.x, w = tid >> 6, lane = tid & 63, quad = lane >> 4, l16 = lane & 15;
  int n0 = blockIdx.x * 128, m0 = blockIdx.y * 64;

  f32x4 acc[2][4];
#pragma unroll
  for (int i = 0; i < 2; ++i)
#pragma unroll
    for (int j = 0; j < 4; ++j) acc[i][j] = (f32x4){0.f, 0.f, 0.f, 0.f};

  int cp = lane & 3, rl = lane >> 2;
  int gcB = (cp ^ ((rl >> 1) & 3)) * 8;
  int xorv = ((l16 >> 1) & 3) * 8;
  int mw = (w & 1) * 32, nw = (w >> 1) * 64;

  // A row handled by this lane (chunk = wave id, rows w*16+rl)
  int am = m0 + w*16 + rl;
  int ab = am >> 11, as = am & 2047;

  auto stageB = [&](int k0, int b){
#pragma unroll
    for (int i = 0; i < 2; ++i){
      int c = w * 2 + i;                      // 8 B-chunks of 16 rows
      gl_lds16(Bw + (size_t)(n0 + c*16 + rl) * 1024 + k0 + gcB,
               &sB[b][c * 512 + lane * 8]);
    }
  };
  auto stageA = [&](int k0, int b){
    int kk = k0 + cp * 8;
    int h = kk >> 6, d = kk & 63;
    size_t r0 = (size_t)(ab*16 + h) * 2048 + as;
    size_t r1 = r0 + 65536;                   // + 32*2048
    union { uint4 v; u16 s[8]; } a0, a1;
    a0.v = *(const uint4*)&OP[r0 * 64 + d];
    a1.v = *(const uint4*)&OP[r1 * 64 + d];
    float invl = 1.f / (LP[r0] + LP[r1]);
    union { uint4 v; u16 s[8]; } o;
#pragma unroll
    for (int j = 0; j < 8; ++j)
      o.s[j] = f2bf((bf2f(a0.s[j]) + bf2f(a1.s[j])) * invl);
    *(uint4*)&sA[b][(w*16 + rl) * 40 + cp * 8] = o.v;   // byte addr row*80+cp*16: 16B-aligned
  };

  stageB(0, 0);
  stageA(0, 0);
  for (int it = 0; it < 32; ++it){
    __syncthreads();
    if (it < 31){
      stageB((it + 1) * 32, (it + 1) & 1);
      stageA((it + 1) * 32, (it + 1) & 1);
    }
    const u16* cA = sA[it & 1];
    const u16* cB = sB[it & 1];
    bf16x8 af[2], bfr[4];
#pragma unroll
    for (int mt = 0; mt < 2; ++mt)
      af[mt] = *(const bf16x8*)&cA[(mw + mt*16 + l16) * 40 + quad * 8];
#pragma unroll
    for (int nt = 0; nt < 4; ++nt)
      bfr[nt] = *(const bf16x8*)&cB[(nw + nt*16 + l16) * 32 + (quad*8 ^ xorv)];
#pragma unroll
    for (int mt = 0; mt < 2; ++mt)
#pragma unroll
      for (int nt = 0; nt < 4; ++nt)
        acc[mt][nt] = MFMA_BF16(af[mt], bfr[nt], acc[mt][nt]);
  }

  int isbf = *flag;
#pragma unroll
  for (int mt = 0; mt < 2; ++mt){
    int row = m0 + mw + mt*16 + quad*4;
#pragma unroll
    for (int nt = 0; nt < 4; ++nt){
      int col = n0 + nw + nt*16 + l16;
      float bv = bias[col];
#pragma unroll
      for (int r = 0; r < 4; ++r){
        float val = acc[mt][nt][r] + bv;
        size_t addr = (size_t)(row + r) * 1024 + col;
        if (isbf) ((u16*)dout)[addr] = f2bf(val);
        else      ((float*)dout)[addr] = val;
      }
    }
  }
}

// ---------------- flash attention v4 (unchanged, verified) ----------------
#define SPT 20

__global__ __launch_bounds__(256, 3)
void attn_kernel(const u16* __restrict__ Q, const u16* __restrict__ K,
                 const u16* __restrict__ Vt, u16* __restrict__ OP,
                 float* __restrict__ LP){
  __shared__ u16 sK[2][4096];
  __shared__ u16 sPT[4][64 * SPT];
  int bh  = blockIdx.x;
  int spl = blockIdx.y;
  int qt  = 15 - (int)blockIdx.z;
  int tid = threadIdx.x, w = tid >> 6, lane = tid & 63, quad = lane >> 4, l16 = lane & 15;
  size_t kbase = (size_t)bh * 2048 * 64;
  size_t vbase = (size_t)bh * 64 * 2048;
  int rowbase = qt * 128 + w * 32;
  u16* spw = &sPT[w][0];

  bf16x8 qf[2][2];
#pragma unroll
  for (int g = 0; g < 2; ++g)
#pragma unroll
    for (int kc = 0; kc < 2; ++kc)
      qf[g][kc] = *(const bf16x8*)(Q + kbase + (size_t)(rowbase + g*16 + l16) * 64 + kc*32 + quad*8);

  f32x4 oaccT[2][4];
  float lsum[2][4];
#pragma unroll
  for (int g = 0; g < 2; ++g)
#pragma unroll
    for (int i = 0; i < 4; ++i){ oaccT[g][i] = (f32x4){0.f,0.f,0.f,0.f}; lsum[g][i] = 0.f; }

  int kt0 = spl ? (qt + 1) : 0;
  int ntiles = qt + 1;

  auto stage = [&](int kt, int b){
    int kcol = kt * 64;
#pragma unroll
    for (int p = 0; p < 2; ++p){
      int slot = w*128 + p*64 + lane;
      int row = slot >> 3, dc = (slot & 7) ^ (row & 7);
      gl_lds16(K + kbase + (size_t)(kcol + row) * 64 + dc*8, &sK[b][(w*128 + p*64) * 8]);
    }
  };

  stage(kt0, 0);
  for (int i = 0; i < ntiles; ++i){
    int kcol = (kt0 + i) * 64;
    __syncthreads();
    if (i + 1 < ntiles) stage(kt0 + i + 1, (i + 1) & 1);
    const u16* bK = sK[i & 1];

    if (kcol <= rowbase + 31){
      bf16x8 vf[4][2];
#pragma unroll
      for (int dn = 0; dn < 4; ++dn)
#pragma unroll
        for (int kc = 0; kc < 2; ++kc)
          vf[dn][kc] = *(const bf16x8*)(Vt + vbase + (size_t)(dn*16 + l16) * 2048
                                        + kcol + kc*32 + quad*8);
      bf16x8 bk[2][4];
#pragma unroll
      for (int kc = 0; kc < 2; ++kc)
#pragma unroll
        for (int nt = 0; nt < 4; ++nt){
          int rw = nt*16 + l16;
          int ch = ((kc*4 + quad) ^ (rw & 7)) * 8;
          bk[kc][nt] = *(const bf16x8*)&bK[rw*64 + ch];
        }
#pragma unroll
      for (int g = 0; g < 2; ++g){
        int G0 = rowbase + g*16;
        if (kcol <= G0 + 15){
          f32x4 sacc[4];
#pragma unroll
          for (int nt = 0; nt < 4; ++nt) sacc[nt] = (f32x4){0.f,0.f,0.f,0.f};
#pragma unroll
          for (int kc = 0; kc < 2; ++kc)
#pragma unroll
            for (int nt = 0; nt < 4; ++nt)
              sacc[nt] = MFMA_BF16(qf[g][kc], bk[kc][nt], sacc[nt]);

          if (kcol + 63 > G0){
#pragma unroll
            for (int nt = 0; nt < 4; ++nt){
              int col = kcol + nt*16 + l16;
              ushort4 pv;
#pragma unroll
              for (int r = 0; r < 4; ++r){
                int row = G0 + quad*4 + r;
                float pp = (col <= row) ? __builtin_amdgcn_exp2f(sacc[nt][r]) : 0.f;
                lsum[g][r] += pp;
                ((u16*)&pv)[r] = f2bf(pp);
              }
              *(ushort4*)&spw[(nt*16 + l16) * SPT + quad*4] = pv;
            }
          } else {
#pragma unroll
            for (int nt = 0; nt < 4; ++nt){
              ushort4 pv;
#pragma unroll
              for (int r = 0; r < 4; ++r){
                float pp = __builtin_amdgcn_exp2f(sacc[nt][r]);
                lsum[g][r] += pp;
                ((u16*)&pv)[r] = f2bf(pp);
              }
              *(ushort4*)&spw[(nt*16 + l16) * SPT + quad*4] = pv;
            }
          }
#pragma unroll
          for (int kc = 0; kc < 2; ++kc){
            bf16x8 pf;
#pragma unroll
            for (int j = 0; j < 8; ++j)
              pf[j] = ((const __bf16*)spw)[(kc*32 + quad*8 + j) * SPT + l16];
#pragma unroll
            for (int dn = 0; dn < 4; ++dn)
              oaccT[g][dn] = MFMA_BF16(vf[dn][kc], pf, oaccT[g][dn]);
          }
        }
      }
    }
  }

  float* scr = (float*)spw;
#pragma unroll
  for (int g = 0; g < 2; ++g)
#pragma unroll
    for (int r = 0; r < 4; ++r){
      float l = lsum[g][r];
      l += __shfl_xor(l, 1); l += __shfl_xor(l, 2);
      l += __shfl_xor(l, 4); l += __shfl_xor(l, 8);
      if (l16 == 0) scr[g*16 + quad*4 + r] = l;
    }
  float lrow[2];
#pragma unroll
  for (int g = 0; g < 2; ++g) lrow[g] = scr[g*16 + l16];

  size_t obase = ((size_t)(spl*32 + bh)) * 2048;
#pragma unroll
  for (int g = 0; g < 2; ++g){
    int row = rowbase + g*16 + l16;
    if (quad == 0) LP[obase + row] = lrow[g];
#pragma unroll
    for (int dn = 0; dn < 4; ++dn){
      ushort4 ov = { f2bf(oaccT[g][dn][0]), f2bf(oaccT[g][dn][1]),
                     f2bf(oaccT[g][dn][2]), f2bf(oaccT[g][dn][3]) };
      *(ushort4*)&OP[(obase + row) * 64 + dn*16 + quad*4] = ov;
    }
  }
}

// ---------------- launcher ----------------
extern "C" void kernel_launch(void* const* d_in, const int* in_sizes, int n_in,
                              void* d_out, int out_size, void* d_ws, size_t ws_size,
                              hipStream_t stream){
  (void)in_sizes; (void)n_in; (void)out_size; (void)ws_size;
  char* ws = (char*)d_ws;
  int*   flag  = (int*)ws;
  u16*   Xbf   = (u16*)(ws + XBF_OFF);
  u16*   Wd    = (u16*)(ws + WD_OFF);
  float* biasf = (float*)(ws + BIAS_OFF);
  u16*   Qb    = (u16*)(ws + QB_OFF);
  u16*   Kb    = (u16*)(ws + KB_OFF);
  u16*   Vt    = (u16*)(ws + VT_OFF);
  u16*   OP    = (u16*)(ws + OP_OFF);
  float* LP    = (float*)(ws + LP_OFF);

  QPtrs ptrs;
  for (int p = 0; p < 4; ++p){
    for (int wi = 0; wi < 4; ++wi) ptrs.w[p*4 + wi] = d_in[2 + p*5 + wi];
    ptrs.b[p] = d_in[2 + p*5 + 4];
  }

  prep_kernel<<<6144, 256, 0, stream>>>(d_in[0], Xbf, ptrs, Wd, biasf, flag);
  gemm_qkv_kernel<<<dim3(24, 32), 256, 0, stream>>>(Xbf, Wd, biasf, Qb, Kb, Vt);
  attn_kernel<<<dim3(32, 2, 16), 256, 0, stream>>>(Qb, Kb, Vt, OP, LP);
  gemm_o_kernel<<<dim3(8, 64), 256, 0, stream>>>(OP, LP, Wd + 3*1048576, biasf + 3072,
                                                 d_out, flag);
}

// Round 10
// 259.092 us; speedup vs baseline: 1.1492x; 1.0009x over previous
//
#include <hip/hip_runtime.h>
#include <stdint.h>

typedef unsigned short u16;
typedef unsigned int   u32;

#define NB   2
#define NS   2048
#define NDIM 1024
#define NH   16
#define NDH  64
// SCALE * log2(e) = 0.125 * 1.4426950408889634
#define QSCALE 0.18033688011112042f

typedef __bf16 bf16x8 __attribute__((ext_vector_type(8)));
typedef float  f32x4  __attribute__((ext_vector_type(4)));

#define MFMA_BF16(a,b,c) __builtin_amdgcn_mfma_f32_16x16x32_bf16((a),(b),(c),0,0,0)

// ---------------- ws layout (bytes) ----------------
#define XBF_OFF   (256)                          // 8 MB x bf16 (used only for fp32 inputs)
#define WD_OFF    (XBF_OFF  + 8*1024*1024)       // 8 MB dense quaternion weights (q,k,v,o)
#define BIAS_OFF  (WD_OFF   + 8*1024*1024)       // 16 KB fp32 biases
#define QB_OFF    (BIAS_OFF + 16384)             // 8 MB Q (bh,s,d) bf16 (roped, pre-scaled)
#define KB_OFF    (QB_OFF   + 8*1024*1024)       // 8 MB K (bh,s,d) (roped)
#define VT_OFF    (KB_OFF   + 8*1024*1024)       // 8 MB V^T (bh,d,s)
#define OP_OFF    (VT_OFF   + 8*1024*1024)       // 16 MB O partials bf16 [split][bh][s][d]
#define LP_OFF    (OP_OFF   + 16*1024*1024)      // 512 KB l partials fp32 [split][bh][s]

__device__ __forceinline__ float bf2f(u16 h){
  union { u32 u; float f; } v; v.u = ((u32)h) << 16; return v.f;
}
__device__ __forceinline__ u16 f2bf(float f){
  union { float f; u32 u; } v; v.f = f;
  u32 r = (v.u >> 16) & 1u;
  return (u16)((v.u + 0x7fffu + r) >> 16);
}
__device__ __forceinline__ float load_val(const void* p, int i, int isbf){
  return isbf ? bf2f(((const u16*)p)[i]) : ((const float*)p)[i];
}
__device__ __forceinline__ void gl_lds16(const u16* g, u16* l){
  __builtin_amdgcn_global_load_lds(
      (__attribute__((address_space(1))) void*)(uintptr_t)g,
      (__attribute__((address_space(3))) void*)(uintptr_t)l,
      16, 0, 0);
}
__device__ __forceinline__ int sane16(u16 h){
  int e = (h >> 7) & 0xFF;
  return ((e > 96 && e < 158) || ((h & 0x7FFF) == 0)) ? 1 : 0;
}

struct QPtrs { const void* w[16]; const void* b[4]; };

// ---------------- prep: dtype vote + (fp32 only) x->bf16 + dense weight build ----------------
__global__ void prep_kernel(const void* __restrict__ xin, u16* __restrict__ xbf,
                            QPtrs ptrs, u16* __restrict__ wd,
                            float* __restrict__ biasf, int* __restrict__ flag){
  __shared__ int cnt;
  int bx = blockIdx.x, tid = threadIdx.x;
  if (tid == 0) cnt = 0;
  __syncthreads();

  if (bx < 2048){
    int t = bx * 256 + tid;
    uint4 v = ((const uint4*)xin)[t];
    const u16* hv = (const u16*)&v;
    int ok = 0;
#pragma unroll
    for (int j = 0; j < 8; ++j) ok += sane16(hv[j]);
    atomicAdd(&cnt, ok);
    __syncthreads();
    int isbf = (cnt > 1700) ? 1 : 0;
    if (bx == 0 && tid == 0) *flag = isbf;
    if (!isbf){
      const float4* f4 = (const float4*)xin;
      float4 a = f4[2*t], b = f4[2*t+1];
      ushort4 lo = { f2bf(a.x), f2bf(a.y), f2bf(a.z), f2bf(a.w) };
      ushort4 hi = { f2bf(b.x), f2bf(b.y), f2bf(b.z), f2bf(b.w) };
      ((ushort4*)xbf)[2*t]   = lo;
      ((ushort4*)xbf)[2*t+1] = hi;
    }
  } else {
    int idx = (bx - 2048) * 256 + tid;
    int n = idx & 255, m = (idx >> 8) & 255, c = (idx >> 16) & 3, p = idx >> 18;
    const u16* probe = (const u16*)ptrs.w[p*4];
    int ok = sane16(probe[tid]) + sane16(probe[tid + 256]);
    atomicAdd(&cnt, ok);
    __syncthreads();
    int isbf = (cnt > 450) ? 1 : 0;
    int src = m * 256 + n;
    float vr = load_val(ptrs.w[p*4+0], src, isbf);
    float vi = load_val(ptrs.w[p*4+1], src, isbf);
    float vj = load_val(ptrs.w[p*4+2], src, isbf);
    float vk = load_val(ptrs.w[p*4+3], src, isbf);
    float o0, o1, o2, o3;
    switch (c){
      case 0:  o0 = vr; o1 = -vi; o2 = -vj; o3 = -vk; break;
      case 1:  o0 = vi; o1 =  vr; o2 = -vj; o3 =  vk; break;
      case 2:  o0 = vj; o1 =  vi; o2 =  vr; o3 = -vk; break;
      default: o0 = vk; o1 = -vi; o2 =  vj; o3 =  vr; break;
    }
    ushort4 sv = { f2bf(o0), f2bf(o1), f2bf(o2), f2bf(o3) };
    *(ushort4*)&wd[(size_t)p * 1048576 + (size_t)(4*m + c) * 1024 + 4*n] = sv;
    if (idx < 4096){
      int pp = idx >> 10, oo = idx & 1023;
      biasf[idx] = load_val(ptrs.b[pp], oo, isbf);
    }
  }
}

// ---------------- GEMM: X*Wqkv^T, fused bias+RoPE epilogue (r6-proven) ----------------
__global__ __launch_bounds__(256)
void gemm_qkv_kernel(const void* __restrict__ xin, const u16* __restrict__ Axbf,
                     const u16* __restrict__ Bw, const float* __restrict__ bias,
                     const int* __restrict__ flag,
                     u16* __restrict__ qb, u16* __restrict__ kb, u16* __restrict__ vt){
  __shared__ u16 sA[2][128 * 32];
  __shared__ u16 sB[2][128 * 32];
  int tid = threadIdx.x, w = tid >> 6, lane = tid & 63, quad = lane >> 4, l16 = lane & 15;
  int n0 = blockIdx.x * 128, m0 = blockIdx.y * 128;
  const u16* A = (*flag) ? (const u16*)xin : Axbf;   // bf16 input: read x directly

  f32x4 acc[4][4];
#pragma unroll
  for (int i = 0; i < 4; ++i)
#pragma unroll
    for (int j = 0; j < 4; ++j) acc[i][j] = (f32x4){0.f, 0.f, 0.f, 0.f};

  int cp = lane & 3, rl = lane >> 2;
  int gc = (cp ^ ((rl >> 1) & 3)) * 8;
  const u16* ga = A  + (size_t)(m0 + w*16 + rl) * 1024 + gc;
  const u16* gb = Bw + (size_t)(n0 + w*16 + rl) * 1024 + gc;
  int ldo = w * 512 + lane * 8;
  int xorv = ((l16 >> 1) & 3) * 8;
  int mw = (w & 1) * 64, nw = (w >> 1) * 64;

  auto stage = [&](int k0, int b){
#pragma unroll
    for (int i = 0; i < 2; ++i){
      gl_lds16(ga + (size_t)i * 65536 + k0, &sA[b][ldo + i * 2048]);
      gl_lds16(gb + (size_t)i * 65536 + k0, &sB[b][ldo + i * 2048]);
    }
  };

  stage(0, 0);
  for (int it = 0; it < 32; ++it){
    __syncthreads();
    if (it < 31) stage((it + 1) * 32, (it + 1) & 1);
    const u16* cA = sA[it & 1];
    const u16* cB = sB[it & 1];
    bf16x8 af[4], bfr[4];
#pragma unroll
    for (int mt = 0; mt < 4; ++mt)
      af[mt] = *(const bf16x8*)&cA[(mw + mt*16 + l16) * 32 + (quad*8 ^ xorv)];
#pragma unroll
    for (int nt = 0; nt < 4; ++nt)
      bfr[nt] = *(const bf16x8*)&cB[(nw + nt*16 + l16) * 32 + (quad*8 ^ xorv)];
#pragma unroll
    for (int mt = 0; mt < 4; ++mt)
#pragma unroll
      for (int nt = 0; nt < 4; ++nt)
        acc[mt][nt] = MFMA_BF16(af[mt], bfr[nt], acc[mt][nt]);
  }

  int proj = n0 >> 10;    // uniform per block
  if (proj == 2){
    // V^T: [bh][d][s]
#pragma unroll
    for (int mt = 0; mt < 4; ++mt){
      int row = m0 + mw + mt*16 + quad*4;
      int b = row >> 11, seq0 = row & 2047;
#pragma unroll
      for (int nt = 0; nt < 4; ++nt){
        int col = n0 + nw + nt*16 + l16;
        int o = col & 1023, h = o >> 6, d = o & 63;
        float bv = bias[col];
        ushort4 pv = { f2bf(acc[mt][nt][0] + bv), f2bf(acc[mt][nt][1] + bv),
                       f2bf(acc[mt][nt][2] + bv), f2bf(acc[mt][nt][3] + bv) };
        *(ushort4*)&vt[((size_t)((b*16 + h) * 64 + d)) * 2048 + seq0] = pv;
      }
    }
  } else {
    // Q/K with fused RoPE: out = co*v + sgn*si*partner (partner = lane xor (ax+1))
    float sc = (proj == 0) ? QSCALE : 1.0f;
    u16* dst = proj ? kb : qb;
    int c = l16 & 3;
#pragma unroll
    for (int nt = 0; nt < 4; ++nt){
      int col = n0 + nw + nt*16 + l16;
      int o = col & 1023, h = o >> 6, d = o & 63;
      int g = d >> 2;
      int ax = g % 3;
      int mask = ax + 1;
      int tbl = (ax == 0) ? 0xA : (ax == 1 ? 0x6 : 0xC);
      float sgn = ((tbl >> c) & 1) ? 1.f : -1.f;
      float inv = __builtin_amdgcn_exp2f(-(float)g * 0.8304820237218405f); // 10000^(-g/16)
      float bv = bias[col];
#pragma unroll
      for (int mt = 0; mt < 4; ++mt){
        int row0 = m0 + mw + mt*16 + quad*4;
        int b = row0 >> 11, s0 = row0 & 2047;
        size_t obase = ((size_t)((b*16 + h) * 2048 + s0)) * 64 + d;
#pragma unroll
        for (int r = 0; r < 4; ++r){
          float v = acc[mt][nt][r] + bv;
          float vp = __shfl_xor(v, mask);
          float ang = (float)(s0 + r) * inv;
          float co = __cosf(ang) * sc;
          float si = __sinf(ang) * sc * sgn;
          dst[obase + (size_t)r * 64] = f2bf(co * v + si * vp);
        }
      }
    }
  }
}

// ---------------- GEMM: (combine ∘ attn-out) * Wo^T -> d_out (r9 version) ----------------
__global__ __launch_bounds__(256)
void gemm_o_kernel(const u16* __restrict__ OP, const float* __restrict__ LP,
                   const u16* __restrict__ Bw, const float* __restrict__ bias,
                   void* __restrict__ dout, const int* __restrict__ flag){
  __shared__ u16 sA[2][64 * 40];
  __shared__ u16 sB[2][128 * 32];
  int tid = threadIdx.x, w = tid >> 6, lane = tid & 63, quad = lane >> 4, l16 = lane & 15;
  int n0 = blockIdx.x * 128, m0 = blockIdx.y * 64;

  f32x4 acc[2][4];
#pragma unroll
  for (int i = 0; i < 2; ++i)
#pragma unroll
    for (int j = 0; j < 4; ++j) acc[i][j] = (f32x4){0.f, 0.f, 0.f, 0.f};

  int cp = lane & 3, rl = lane >> 2;
  int gcB = (cp ^ ((rl >> 1) & 3)) * 8;
  int xorv = ((l16 >> 1) & 3) * 8;
  int mw = (w & 1) * 32, nw = (w >> 1) * 64;

  int am = m0 + w*16 + rl;
  int ab = am >> 11, as = am & 2047;

  auto stageB = [&](int k0, int b){
#pragma unroll
    for (int i = 0; i < 2; ++i){
      int c = w * 2 + i;
      gl_lds16(Bw + (size_t)(n0 + c*16 + rl) * 1024 + k0 + gcB,
               &sB[b][c * 512 + lane * 8]);
    }
  };
  auto stageA = [&](int k0, int b){
    int kk = k0 + cp * 8;
    int h = kk >> 6, d = kk & 63;
    size_t r0 = (size_t)(ab*16 + h) * 2048 + as;
    size_t r1 = r0 + 65536;
    union { uint4 v; u16 s[8]; } a0, a1;
    a0.v = *(const uint4*)&OP[r0 * 64 + d];
    a1.v = *(const uint4*)&OP[r1 * 64 + d];
    float invl = 1.f / (LP[r0] + LP[r1]);
    union { uint4 v; u16 s[8]; } o;
#pragma unroll
    for (int j = 0; j < 8; ++j)
      o.s[j] = f2bf((bf2f(a0.s[j]) + bf2f(a1.s[j])) * invl);
    *(uint4*)&sA[b][(w*16 + rl) * 40 + cp * 8] = o.v;
  };

  stageB(0, 0);
  stageA(0, 0);
  for (int it = 0; it < 32; ++it){
    __syncthreads();
    if (it < 31){
      stageB((it + 1) * 32, (it + 1) & 1);
      stageA((it + 1) * 32, (it + 1) & 1);
    }
    const u16* cA = sA[it & 1];
    const u16* cB = sB[it & 1];
    bf16x8 af[2], bfr[4];
#pragma unroll
    for (int mt = 0; mt < 2; ++mt)
      af[mt] = *(const bf16x8*)&cA[(mw + mt*16 + l16) * 40 + quad * 8];
#pragma unroll
    for (int nt = 0; nt < 4; ++nt)
      bfr[nt] = *(const bf16x8*)&cB[(nw + nt*16 + l16) * 32 + (quad*8 ^ xorv)];
#pragma unroll
    for (int mt = 0; mt < 2; ++mt)
#pragma unroll
      for (int nt = 0; nt < 4; ++nt)
        acc[mt][nt] = MFMA_BF16(af[mt], bfr[nt], acc[mt][nt]);
  }

  int isbf = *flag;
#pragma unroll
  for (int mt = 0; mt < 2; ++mt){
    int row = m0 + mw + mt*16 + quad*4;
#pragma unroll
    for (int nt = 0; nt < 4; ++nt){
      int col = n0 + nw + nt*16 + l16;
      float bv = bias[col];
#pragma unroll
      for (int r = 0; r < 4; ++r){
        float val = acc[mt][nt][r] + bv;
        size_t addr = (size_t)(row + r) * 1024 + col;
        if (isbf) ((u16*)dout)[addr] = f2bf(val);
        else      ((float*)dout)[addr] = val;
      }
    }
  }
}

// ---------------- flash attention v5: paired kt-tile staging (half the barriers) ----------------
#define SPT 20

__global__ __launch_bounds__(256, 3)
void attn_kernel(const u16* __restrict__ Q, const u16* __restrict__ K,
                 const u16* __restrict__ Vt, u16* __restrict__ OP,
                 float* __restrict__ LP){
  __shared__ u16 sK[2][8192];            // 2 buffers x 2 kt-tiles (128 rows x 64)
  __shared__ u16 sPT[4][64 * SPT];
  int bh  = blockIdx.x;
  int spl = blockIdx.y;
  int qt  = 15 - (int)blockIdx.z;
  int tid = threadIdx.x, w = tid >> 6, lane = tid & 63, quad = lane >> 4, l16 = lane & 15;
  size_t kbase = (size_t)bh * 2048 * 64;
  size_t vbase = (size_t)bh * 64 * 2048;
  int rowbase = qt * 128 + w * 32;
  u16* spw = &sPT[w][0];

  bf16x8 qf[2][2];
#pragma unroll
  for (int g = 0; g < 2; ++g)
#pragma unroll
    for (int kc = 0; kc < 2; ++kc)
      qf[g][kc] = *(const bf16x8*)(Q + kbase + (size_t)(rowbase + g*16 + l16) * 64 + kc*32 + quad*8);

  f32x4 oaccT[2][4];
  float lsum[2][4];
#pragma unroll
  for (int g = 0; g < 2; ++g)
#pragma unroll
    for (int i = 0; i < 4; ++i){ oaccT[g][i] = (f32x4){0.f,0.f,0.f,0.f}; lsum[g][i] = 0.f; }

  int kt0 = spl ? (qt + 1) : 0;
  int ntiles = qt + 1;
  int npairs = (ntiles + 1) >> 1;
  int lim = (kt0 + ntiles) * 64 - 1;     // last valid K row for this split

  // stage pair pi (128 rows) into buffer b; clamped rows beyond lim are never read
  auto stage2 = [&](int pi, int b){
    int base0 = (kt0 + 2*pi) * 64;
#pragma unroll
    for (int p = 0; p < 4; ++p){
      int slot = w*256 + p*64 + lane;     // 0..1023 = 128 rows x 8 chunks
      int row = slot >> 3, dc = (slot & 7) ^ (row & 7);
      int grow = min(base0 + row, lim);
      gl_lds16(K + kbase + (size_t)grow * 64 + dc*8, &sK[b][(w*256 + p*64) * 8]);
    }
  };

  stage2(0, 0);
  for (int pi = 0; pi < npairs; ++pi){
    __syncthreads();
    if (pi + 1 < npairs) stage2(pi + 1, (pi + 1) & 1);
    const u16* pK = sK[pi & 1];

#pragma unroll
    for (int j = 0; j < 2; ++j){
      int i = 2*pi + j;
      if (i >= ntiles) break;
      int kcol = (kt0 + i) * 64;
      if (kcol > rowbase + 31) continue;
      const u16* bK = pK + j * 4096;

      bf16x8 vf[4][2];
#pragma unroll
      for (int dn = 0; dn < 4; ++dn)
#pragma unroll
        for (int kc = 0; kc < 2; ++kc)
          vf[dn][kc] = *(const bf16x8*)(Vt + vbase + (size_t)(dn*16 + l16) * 2048
                                        + kcol + kc*32 + quad*8);
      bf16x8 bk[2][4];
#pragma unroll
      for (int kc = 0; kc < 2; ++kc)
#pragma unroll
        for (int nt = 0; nt < 4; ++nt){
          int rw = nt*16 + l16;
          int ch = ((kc*4 + quad) ^ (rw & 7)) * 8;
          bk[kc][nt] = *(const bf16x8*)&bK[rw*64 + ch];
        }
#pragma unroll
      for (int g = 0; g < 2; ++g){
        int G0 = rowbase + g*16;
        if (kcol <= G0 + 15){
          f32x4 sacc[4];
#pragma unroll
          for (int nt = 0; nt < 4; ++nt) sacc[nt] = (f32x4){0.f,0.f,0.f,0.f};
#pragma unroll
          for (int kc = 0; kc < 2; ++kc)
#pragma unroll
            for (int nt = 0; nt < 4; ++nt)
              sacc[nt] = MFMA_BF16(qf[g][kc], bk[kc][nt], sacc[nt]);

          if (kcol + 63 > G0){
#pragma unroll
            for (int nt = 0; nt < 4; ++nt){
              int col = kcol + nt*16 + l16;
              ushort4 pv;
#pragma unroll
              for (int r = 0; r < 4; ++r){
                int row = G0 + quad*4 + r;
                float pp = (col <= row) ? __builtin_amdgcn_exp2f(sacc[nt][r]) : 0.f;
                lsum[g][r] += pp;
                ((u16*)&pv)[r] = f2bf(pp);
              }
              *(ushort4*)&spw[(nt*16 + l16) * SPT + quad*4] = pv;
            }
          } else {
#pragma unroll
            for (int nt = 0; nt < 4; ++nt){
              ushort4 pv;
#pragma unroll
              for (int r = 0; r < 4; ++r){
                float pp = __builtin_amdgcn_exp2f(sacc[nt][r]);
                lsum[g][r] += pp;
                ((u16*)&pv)[r] = f2bf(pp);
              }
              *(ushort4*)&spw[(nt*16 + l16) * SPT + quad*4] = pv;
            }
          }
#pragma unroll
          for (int kc = 0; kc < 2; ++kc){
            bf16x8 pf;
#pragma unroll
            for (int jj = 0; jj < 8; ++jj)
              pf[jj] = ((const __bf16*)spw)[(kc*32 + quad*8 + jj) * SPT + l16];
#pragma unroll
            for (int dn = 0; dn < 4; ++dn)
              oaccT[g][dn] = MFMA_BF16(vf[dn][kc], pf, oaccT[g][dn]);
          }
        }
      }
    }
  }

  float* scr = (float*)spw;
#pragma unroll
  for (int g = 0; g < 2; ++g)
#pragma unroll
    for (int r = 0; r < 4; ++r){
      float l = lsum[g][r];
      l += __shfl_xor(l, 1); l += __shfl_xor(l, 2);
      l += __shfl_xor(l, 4); l += __shfl_xor(l, 8);
      if (l16 == 0) scr[g*16 + quad*4 + r] = l;
    }
  float lrow[2];
#pragma unroll
  for (int g = 0; g < 2; ++g) lrow[g] = scr[g*16 + l16];

  size_t obase = ((size_t)(spl*32 + bh)) * 2048;
#pragma unroll
  for (int g = 0; g < 2; ++g){
    int row = rowbase + g*16 + l16;
    if (quad == 0) LP[obase + row] = lrow[g];
#pragma unroll
    for (int dn = 0; dn < 4; ++dn){
      ushort4 ov = { f2bf(oaccT[g][dn][0]), f2bf(oaccT[g][dn][1]),
                     f2bf(oaccT[g][dn][2]), f2bf(oaccT[g][dn][3]) };
      *(ushort4*)&OP[(obase + row) * 64 + dn*16 + quad*4] = ov;
    }
  }
}

// ---------------- launcher ----------------
extern "C" void kernel_launch(void* const* d_in, const int* in_sizes, int n_in,
                              void* d_out, int out_size, void* d_ws, size_t ws_size,
                              hipStream_t stream){
  (void)in_sizes; (void)n_in; (void)out_size; (void)ws_size;
  char* ws = (char*)d_ws;
  int*   flag  = (int*)ws;
  u16*   Xbf   = (u16*)(ws + XBF_OFF);
  u16*   Wd    = (u16*)(ws + WD_OFF);
  float* biasf = (float*)(ws + BIAS_OFF);
  u16*   Qb    = (u16*)(ws + QB_OFF);
  u16*   Kb    = (u16*)(ws + KB_OFF);
  u16*   Vt    = (u16*)(ws + VT_OFF);
  u16*   OP    = (u16*)(ws + OP_OFF);
  float* LP    = (float*)(ws + LP_OFF);

  QPtrs ptrs;
  for (int p = 0; p < 4; ++p){
    for (int wi = 0; wi < 4; ++wi) ptrs.w[p*4 + wi] = d_in[2 + p*5 + wi];
    ptrs.b[p] = d_in[2 + p*5 + 4];
  }

  prep_kernel<<<6144, 256, 0, stream>>>(d_in[0], Xbf, ptrs, Wd, biasf, flag);
  gemm_qkv_kernel<<<dim3(24, 32), 256, 0, stream>>>(d_in[0], Xbf, Wd, biasf, flag,
                                                    Qb, Kb, Vt);
  attn_kernel<<<dim3(32, 2, 16), 256, 0, stream>>>(Qb, Kb, Vt, OP, LP);
  gemm_o_kernel<<<dim3(8, 64), 256, 0, stream>>>(OP, LP, Wd + 3*1048576, biasf + 3072,
                                                 d_out, flag);
}